// Round 3
// baseline (1813.018 us; speedup 1.0000x reference)
//
#include <hip/hip_runtime.h>
#include <hip/hip_bf16.h>

// ---- problem constants ----
#define BB_ 32      // batch
#define PP_ 196     // pixels
#define DD_ 2048    // encoder dim
#define HH_ 512     // hidden
#define VV_ 30000   // vocab
#define TT_ 19      // timesteps
#define KX_ 2560    // H + D
#define KG_ 3072    // H + D + H
#define NTV_ 1875   // VV_/16 n-tiles for out GEMM
#define NBOUT_ 469  // blocks for out GEMM part (469*4 waves >= 1875)

typedef __attribute__((ext_vector_type(8))) short bf16x8;   // 8 bf16 (4 VGPRs)
typedef __attribute__((ext_vector_type(4))) float f32x4;

__device__ __forceinline__ unsigned short bf16b(float x) {
    __hip_bfloat16 h = __float2bfloat16(x);
    unsigned short u; __builtin_memcpy(&u, &h, 2); return u;
}
__device__ __forceinline__ float b2f(unsigned short u) {
    unsigned int v = (unsigned int)u << 16;
    return __uint_as_float(v);
}
__device__ __forceinline__ float sigf(float x) { return 1.f / (1.f + __expf(-x)); }
// tanh(x) = 1 - 2/(e^{2x}+1); correct limits at +/-inf
__device__ __forceinline__ float ftanh(float x) {
    return 1.f - 2.f / (__expf(2.f * x) + 1.f);
}

// ---------------- conversion kernels ----------------

// fp32 -> bf16, 8 elements/thread (for img)
__global__ __launch_bounds__(256) void k_cvt8(const float* __restrict__ src,
                                              unsigned short* __restrict__ dst) {
    size_t i0 = ((size_t)blockIdx.x * 256 + threadIdx.x) * 8;
    float4 a = *(const float4*)&src[i0];
    float4 b = *(const float4*)&src[i0 + 4];
    bf16x8 v;
    v[0]=bf16b(a.x); v[1]=bf16b(a.y); v[2]=bf16b(a.z); v[3]=bf16b(a.w);
    v[4]=bf16b(b.x); v[5]=bf16b(b.y); v[6]=bf16b(b.z); v[7]=bf16b(b.w);
    *(bf16x8*)&dst[i0] = v;
}

// Pre-fragment a row-major f32 W[K][N] into per-lane MFMA B-fragment order.
// Fragment unit f = ((nt*(K/32) + ks)*64 + lane); lane=16g+r holds
// B[ks*32+8g+i][nt*16+r], i=0..7 -> one 16B store per thread.
// n-split: col n < NA reads A[k][n] (stride NA), else Bp[k][n-NA] (stride NB).
__global__ __launch_bounds__(256) void k_cvt_nsplit(const float* __restrict__ A, int NA,
        const float* __restrict__ Bp, int NB, int K, unsigned short* __restrict__ dst) {
    int gid = blockIdx.x * 256 + threadIdx.x;
    int lane = gid & 63, rest = gid >> 6;
    int KS = K >> 5;
    int ks = rest % KS, nt = rest / KS;
    int g = lane >> 4, r = lane & 15;
    int k0 = ks * 32 + g * 8;
    int n = nt * 16 + r;
    const float* src; int stride, col;
    if (n < NA) { src = A; stride = NA; col = n; }
    else        { src = Bp; stride = NB; col = n - NA; }
    bf16x8 v;
#pragma unroll
    for (int i = 0; i < 8; i++)
        v[i] = bf16b(src[(size_t)(k0 + i) * stride + col]);
    *(bf16x8*)&dst[(size_t)gid * 8] = v;
}

// k-split: row k < KA reads A[k][n], else Bp[k-KA][n]; both width N.
__global__ __launch_bounds__(256) void k_cvt_ksplit(const float* __restrict__ A, int KA,
        const float* __restrict__ Bp, int K, int N, unsigned short* __restrict__ dst) {
    int gid = blockIdx.x * 256 + threadIdx.x;
    int lane = gid & 63, rest = gid >> 6;
    int KS = K >> 5;
    int ks = rest % KS, nt = rest / KS;
    int g = lane >> 4, r = lane & 15;
    int k0 = ks * 32 + g * 8;
    int n = nt * 16 + r;
    bf16x8 v;
#pragma unroll
    for (int i = 0; i < 8; i++) {
        int k = k0 + i;
        const float* src = (k < KA) ? &A[(size_t)k * N] : &Bp[(size_t)(k - KA) * N];
        v[i] = bf16b(src[n]);
    }
    *(bf16x8*)&dst[(size_t)gid * 8] = v;
}

// ---------------- precompute ----------------

__global__ __launch_bounds__(256) void k_meanpool(const unsigned short* __restrict__ imgb,
                                                  float* __restrict__ avg) {
    int idx = blockIdx.x * 256 + threadIdx.x;       // B*D = 65536
    int b = idx >> 11, d = idx & 2047;
    const unsigned short* p = imgb + (size_t)b * PP_ * DD_ + d;
    float s = 0.f;
    for (int i = 0; i < PP_; i++) s += b2f(p[(size_t)i * DD_]);
    avg[idx] = s * (1.0f / PP_);
}

__global__ __launch_bounds__(256) void k_init(const float* __restrict__ avg,
        const float* __restrict__ Wh, const float* __restrict__ bh,
        const float* __restrict__ Wc, const float* __restrict__ bc,
        float* __restrict__ c, unsigned short* __restrict__ hb,
        unsigned short* __restrict__ xhb) {
    int idx = blockIdx.x * 256 + threadIdx.x;       // 2*B*H
    int which = idx >> 14;
    int r = idx & 16383;
    int b = r >> 9, j = r & 511;
    const float* W = which ? Wc : Wh;
    const float* avgb = avg + b * DD_;
    float acc = which ? bc[j] : bh[j];
    for (int d = 0; d < DD_; d++) acc += avgb[d] * W[(size_t)d * HH_ + j];
    float v = tanhf(acc);
    if (which) c[r] = v;
    else { hb[r] = bf16b(v); xhb[b * KG_ + KX_ + j] = bf16b(v); }
}

// att_img = img @ W_att_img + b : [6272,2048]x[2048,512], wave tile 32m x 32n
__global__ __launch_bounds__(256) void k_attimg_mfma(const unsigned short* __restrict__ imgb,
        const unsigned short* __restrict__ waf, const float* __restrict__ bias,
        float* __restrict__ Cout) {
    int wid = blockIdx.x * 4 + (threadIdx.x >> 6);   // 0..3135
    int lane = threadIdx.x & 63;
    int g = lane >> 4, r = lane & 15;
    int mblk = wid >> 4, nblk = wid & 15;
    int m0 = mblk * 32, nt0 = nblk * 2;
    f32x4 acc[2][2] = {};
    const unsigned short* a_base = imgb + (size_t)(m0 + r) * DD_ + g * 8;
#pragma unroll 4
    for (int ks = 0; ks < DD_ / 32; ks++) {
        bf16x8 a0 = *(const bf16x8*)(a_base + ks * 32);
        bf16x8 a1 = *(const bf16x8*)(a_base + 16 * DD_ + ks * 32);
        bf16x8 b0 = *(const bf16x8*)(waf + ((size_t)((nt0 + 0) * 64 + ks) * 64 + lane) * 8);
        bf16x8 b1 = *(const bf16x8*)(waf + ((size_t)((nt0 + 1) * 64 + ks) * 64 + lane) * 8);
        acc[0][0] = __builtin_amdgcn_mfma_f32_16x16x32_bf16(a0, b0, acc[0][0], 0, 0, 0);
        acc[0][1] = __builtin_amdgcn_mfma_f32_16x16x32_bf16(a0, b1, acc[0][1], 0, 0, 0);
        acc[1][0] = __builtin_amdgcn_mfma_f32_16x16x32_bf16(a1, b0, acc[1][0], 0, 0, 0);
        acc[1][1] = __builtin_amdgcn_mfma_f32_16x16x32_bf16(a1, b1, acc[1][1], 0, 0, 0);
    }
#pragma unroll
    for (int mi = 0; mi < 2; mi++)
#pragma unroll
        for (int ni = 0; ni < 2; ni++) {
            int n = (nt0 + ni) * 16 + r;
            float bn = bias[n];
#pragma unroll
            for (int j = 0; j < 4; j++) {
                int m = m0 + 16 * mi + 4 * g + j;
                Cout[(size_t)m * HH_ + n] = acc[mi][ni][j] + bn;
            }
        }
}

// ---------------- per-step kernels ----------------

// [hWatt | gate] = h @ [Wah | Wfb] (+bias, sigmoid on gate part); wid = n-tile
__device__ __forceinline__ void hmats_body(int wid, int lane,
        const unsigned short* __restrict__ hb, const unsigned short* __restrict__ whf,
        const float* __restrict__ bah, const float* __restrict__ bfb,
        float* __restrict__ hWatt, float* __restrict__ gate) {
    int g = lane >> 4, r = lane & 15;
    f32x4 acc[2] = {};
    const unsigned short* a_base = hb + (size_t)r * HH_ + g * 8;
#pragma unroll
    for (int ks = 0; ks < HH_ / 32; ks++) {
        bf16x8 a0 = *(const bf16x8*)(a_base + ks * 32);
        bf16x8 a1 = *(const bf16x8*)(a_base + 16 * HH_ + ks * 32);
        bf16x8 bf = *(const bf16x8*)(whf + ((size_t)(wid * 16 + ks) * 64 + lane) * 8);
        acc[0] = __builtin_amdgcn_mfma_f32_16x16x32_bf16(a0, bf, acc[0], 0, 0, 0);
        acc[1] = __builtin_amdgcn_mfma_f32_16x16x32_bf16(a1, bf, acc[1], 0, 0, 0);
    }
    int n = wid * 16 + r;
#pragma unroll
    for (int a = 0; a < 2; a++)
#pragma unroll
        for (int j = 0; j < 4; j++) {
            int m = 16 * a + 4 * g + j;
            float v = acc[a][j];
            if (n < HH_) hWatt[m * HH_ + n] = v + bah[n];
            else gate[m * DD_ + (n - HH_)] = sigf(v + bfb[n - HH_]);
        }
}

__global__ __launch_bounds__(256) void k_hmats_mfma(const unsigned short* __restrict__ hb,
        const unsigned short* __restrict__ whf, const float* __restrict__ bah,
        const float* __restrict__ bfb, float* __restrict__ hWatt, float* __restrict__ gate) {
    int wid = blockIdx.x * 4 + (threadIdx.x >> 6);
    hmats_body(wid, threadIdx.x & 63, hb, whf, bah, bfb, hWatt, gate);
}

// e[b,p] = v . tanh(att_img[b,p,:] + hWatt[b,:]) + b_v   (wave per p)
__global__ __launch_bounds__(256) void k_energy(const float* __restrict__ att_img,
        const float* __restrict__ hWatt, const float* __restrict__ v_att,
        const float* __restrict__ b_v, float* __restrict__ e) {
    int wave = threadIdx.x >> 6, lane = threadIdx.x & 63;
    int gp = blockIdx.x * 4 + wave;
    int b = gp / PP_;
    const float* ai = att_img + (size_t)gp * HH_;
    const float* hw = hWatt + (size_t)b * HH_;
    float acc = 0.f;
#pragma unroll
    for (int rep = 0; rep < 2; rep++) {
        int j = rep * 256 + lane * 4;
        float4 a4 = *(const float4*)&ai[j];
        float4 h4 = *(const float4*)&hw[j];
        float4 v4 = *(const float4*)&v_att[j];
        acc += v4.x * ftanh(a4.x + h4.x);
        acc += v4.y * ftanh(a4.y + h4.y);
        acc += v4.z * ftanh(a4.z + h4.z);
        acc += v4.w * ftanh(a4.w + h4.w);
    }
    for (int off = 32; off > 0; off >>= 1) acc += __shfl_down(acc, off);
    if (lane == 0) e[gp] = acc + b_v[0];
}

// softmax over p (replicated per 256-wide d-chunk), context, x assembly (bf16)
// grid (B, 8); dc==0 also writes alphas + emb; dc==1 copies h -> xhb tail
__global__ __launch_bounds__(128) void k_softmax_ctx(const float* __restrict__ e,
        const unsigned short* __restrict__ imgb, const float* __restrict__ gate,
        const float* __restrict__ Emb, const int* __restrict__ captions, int t,
        unsigned short* __restrict__ xhb, const unsigned short* __restrict__ hb,
        float* __restrict__ alpha_out) {
    __shared__ float sa[PP_];
    __shared__ float red[128];
    const int b = blockIdx.x, dc = blockIdx.y, tid = threadIdx.x;
    const float* eb = e + b * PP_;
    float e0 = eb[tid];
    float e1 = (tid < PP_ - 128) ? eb[128 + tid] : -1e30f;
    red[tid] = fmaxf(e0, e1);
    __syncthreads();
    for (int s = 64; s > 0; s >>= 1) {
        if (tid < s) red[tid] = fmaxf(red[tid], red[tid + s]);
        __syncthreads();
    }
    float mx = red[0];
    __syncthreads();
    float p0 = __expf(e0 - mx);
    float p1 = (tid < PP_ - 128) ? __expf(e1 - mx) : 0.f;
    red[tid] = p0 + p1;
    __syncthreads();
    for (int s = 64; s > 0; s >>= 1) {
        if (tid < s) red[tid] += red[tid + s];
        __syncthreads();
    }
    float inv = 1.f / red[0];
    sa[tid] = p0 * inv;
    if (tid < PP_ - 128) sa[128 + tid] = p1 * inv;
    __syncthreads();
    // context for this 256-wide d-chunk (2 bf16 per thread per p)
    int d0 = dc * 256 + tid * 2;
    const unsigned short* ib = imgb + (size_t)b * PP_ * DD_ + d0;
    float acc0 = 0.f, acc1 = 0.f;
#pragma unroll 4
    for (int p = 0; p < PP_; p++) {
        unsigned int v = *(const unsigned int*)&ib[(size_t)p * DD_];
        float s = sa[p];
        acc0 += s * __uint_as_float(v << 16);
        acc1 += s * __uint_as_float(v & 0xffff0000u);
    }
    float2 gv = *(const float2*)&gate[b * DD_ + d0];
    unsigned int packed = (unsigned int)bf16b(gv.x * acc0)
                        | ((unsigned int)bf16b(gv.y * acc1) << 16);
    *(unsigned int*)&xhb[b * KG_ + HH_ + d0] = packed;
    if (dc == 0) {
        float* ao = alpha_out + ((size_t)b * TT_ + t) * PP_;
        ao[tid] = sa[tid];
        if (tid < PP_ - 128) ao[128 + tid] = sa[128 + tid];
        int tok = captions[b * 20 + t];
        float4 ev = *(const float4*)&Emb[(size_t)tok * HH_ + tid * 4];
        unsigned short* xo = xhb + b * KG_ + tid * 4;
        xo[0] = bf16b(ev.x); xo[1] = bf16b(ev.y);
        xo[2] = bf16b(ev.z); xo[3] = bf16b(ev.w);
    } else if (dc == 1) {
        // copy h (bf16) into xh tail — safe here (ordered before k_gateslstm)
        *(uint2*)&xhb[b * KG_ + KX_ + tid * 4] =
            *(const uint2*)&hb[b * HH_ + tid * 4];
    }
}

// fused gates GEMM (x@[Wih;Whh]) + LSTM pointwise.
// 32 blocks (16-wide j slices); wave q owns gate-quadrant q. Writes c, hb ONLY.
__global__ __launch_bounds__(256) void k_gateslstm(const unsigned short* __restrict__ xhb,
        const unsigned short* __restrict__ wgf, const float* __restrict__ bih,
        const float* __restrict__ bhh, float* __restrict__ c,
        unsigned short* __restrict__ hb) {
    __shared__ float lds_g[4][BB_][16];
    int q = threadIdx.x >> 6;
    int lane = threadIdx.x & 63;
    int g = lane >> 4, r = lane & 15;
    int jb = blockIdx.x;                 // 0..31
    int nt = q * 32 + jb;                // n-tile within [0,128)
    f32x4 acc[2] = {};
    const unsigned short* a_base = xhb + (size_t)r * KG_ + g * 8;
#pragma unroll 4
    for (int ks = 0; ks < KG_ / 32; ks++) {
        bf16x8 a0 = *(const bf16x8*)(a_base + ks * 32);
        bf16x8 a1 = *(const bf16x8*)(a_base + 16 * KG_ + ks * 32);
        bf16x8 bf = *(const bf16x8*)(wgf + ((size_t)(nt * 96 + ks) * 64 + lane) * 8);
        acc[0] = __builtin_amdgcn_mfma_f32_16x16x32_bf16(a0, bf, acc[0], 0, 0, 0);
        acc[1] = __builtin_amdgcn_mfma_f32_16x16x32_bf16(a1, bf, acc[1], 0, 0, 0);
    }
#pragma unroll
    for (int a = 0; a < 2; a++)
#pragma unroll
        for (int j = 0; j < 4; j++)
            lds_g[q][16 * a + 4 * g + j][r] = acc[a][j];
    __syncthreads();
#pragma unroll
    for (int it = 0; it < 2; it++) {
        int e2 = threadIdx.x + it * 256;          // 0..511
        int m = e2 >> 4, jc = e2 & 15;
        int jg = jb * 16 + jc;                    // 0..511
        float gi = lds_g[0][m][jc] + bih[jg] + bhh[jg];
        float gf = lds_g[1][m][jc] + bih[HH_ + jg] + bhh[HH_ + jg];
        float gg = lds_g[2][m][jc] + bih[2 * HH_ + jg] + bhh[2 * HH_ + jg];
        float go = lds_g[3][m][jc] + bih[3 * HH_ + jg] + bhh[3 * HH_ + jg];
        int ci = m * HH_ + jg;
        float cn = sigf(gf) * c[ci] + sigf(gi) * ftanh(gg);
        float hn = sigf(go) * ftanh(cn);
        c[ci] = cn;
        hb[ci] = bf16b(hn);
    }
}

// fused: blocks [0,469) -> preds[:,t,:] = h@W_out + b_out ; blocks [469,509)
// -> hWatt/gate for the NEXT step (same input h, disjoint outputs)
__global__ __launch_bounds__(256) void k_out_hmats(const unsigned short* __restrict__ hb,
        const unsigned short* __restrict__ wof, const float* __restrict__ bout,
        const unsigned short* __restrict__ whf, const float* __restrict__ bah,
        const float* __restrict__ bfb, float* __restrict__ preds,
        float* __restrict__ hWatt, float* __restrict__ gate, int t) {
    int lane = threadIdx.x & 63;
    int wv = threadIdx.x >> 6;
    if (blockIdx.x >= NBOUT_) {
        int wid = (blockIdx.x - NBOUT_) * 4 + wv;   // 0..159
        hmats_body(wid, lane, hb, whf, bah, bfb, hWatt, gate);
        return;
    }
    int nt = blockIdx.x * 4 + wv;
    if (nt >= NTV_) return;
    int g = lane >> 4, r = lane & 15;
    f32x4 acc[2] = {};
    const unsigned short* a_base = hb + (size_t)r * HH_ + g * 8;
#pragma unroll
    for (int ks = 0; ks < HH_ / 32; ks++) {
        bf16x8 a0 = *(const bf16x8*)(a_base + ks * 32);
        bf16x8 a1 = *(const bf16x8*)(a_base + 16 * HH_ + ks * 32);
        bf16x8 bf = *(const bf16x8*)(wof + ((size_t)(nt * 16 + ks) * 64 + lane) * 8);
        acc[0] = __builtin_amdgcn_mfma_f32_16x16x32_bf16(a0, bf, acc[0], 0, 0, 0);
        acc[1] = __builtin_amdgcn_mfma_f32_16x16x32_bf16(a1, bf, acc[1], 0, 0, 0);
    }
    int n = nt * 16 + r;
    float bn = bout[n];
#pragma unroll
    for (int a = 0; a < 2; a++)
#pragma unroll
        for (int j = 0; j < 4; j++) {
            int m = 16 * a + 4 * g + j;
            preds[((size_t)m * TT_ + t) * VV_ + n] = acc[a][j] + bn;
        }
}

// ---------------- launcher ----------------

extern "C" void kernel_launch(void* const* d_in, const int* in_sizes, int n_in,
                              void* d_out, int out_size, void* d_ws, size_t ws_size,
                              hipStream_t stream) {
    const float* img     = (const float*)d_in[0];
    const int*   caps    = (const int*)d_in[1];
    const float* Wih     = (const float*)d_in[2];
    const float* Whh     = (const float*)d_in[3];
    const float* bih     = (const float*)d_in[4];
    const float* bhh     = (const float*)d_in[5];
    const float* Winh    = (const float*)d_in[6];
    const float* binh    = (const float*)d_in[7];
    const float* Winc    = (const float*)d_in[8];
    const float* binc    = (const float*)d_in[9];
    const float* Wfb     = (const float*)d_in[10];
    const float* bfb     = (const float*)d_in[11];
    const float* Wout    = (const float*)d_in[12];
    const float* bout    = (const float*)d_in[13];
    const float* Wai     = (const float*)d_in[14];
    const float* bai     = (const float*)d_in[15];
    const float* Wah     = (const float*)d_in[16];
    const float* bah     = (const float*)d_in[17];
    const float* v_att   = (const float*)d_in[18];
    const float* b_v     = (const float*)d_in[19];
    const float* Emb     = (const float*)d_in[20];

    float* preds  = (float*)d_out;                               // [B,T,V]
    float* alphas = (float*)d_out + (size_t)BB_ * TT_ * VV_;     // [B,T,P]

    // ---- workspace layout (256B aligned) ----
    char* w = (char*)d_ws;
    size_t off = 0;
    auto alloc = [&](size_t bytes) {
        char* p = w + off;
        off += (bytes + 255) & ~(size_t)255;
        return p;
    };
    unsigned short* imgb = (unsigned short*)alloc((size_t)BB_ * PP_ * DD_ * 2); // 25.7MB
    unsigned short* wof  = (unsigned short*)alloc((size_t)HH_ * VV_ * 2);       // 30.7MB
    unsigned short* wgf  = (unsigned short*)alloc((size_t)KG_ * 2048 * 2);      // 12.6MB
    unsigned short* waf  = (unsigned short*)alloc((size_t)DD_ * HH_ * 2);       // 2.1MB
    unsigned short* whf  = (unsigned short*)alloc((size_t)HH_ * KX_ * 2);       // 2.6MB
    float* att_img = (float*)alloc((size_t)BB_ * PP_ * HH_ * 4);                // 12.8MB
    float* avg     = (float*)alloc((size_t)BB_ * DD_ * 4);
    float* c       = (float*)alloc((size_t)BB_ * HH_ * 4);
    float* hWatt   = (float*)alloc((size_t)BB_ * HH_ * 4);
    float* gate    = (float*)alloc((size_t)BB_ * DD_ * 4);
    float* e       = (float*)alloc((size_t)BB_ * PP_ * 4);
    unsigned short* hb  = (unsigned short*)alloc((size_t)BB_ * HH_ * 2);
    unsigned short* xhb = (unsigned short*)alloc((size_t)BB_ * KG_ * 2);
    (void)ws_size;

    // ---- one-time conversions / precompute ----
    k_cvt8<<<6272, 256, 0, stream>>>(img, imgb);
    k_cvt_nsplit<<<7500, 256, 0, stream>>>(Wout, VV_, Wout, 0, HH_, wof);
    k_cvt_nsplit<<<512, 256, 0, stream>>>(Wai, HH_, Wai, 0, DD_, waf);
    k_cvt_nsplit<<<640, 256, 0, stream>>>(Wah, HH_, Wfb, DD_, HH_, whf);
    k_cvt_ksplit<<<3072, 256, 0, stream>>>(Wih, KX_, Whh, KG_, 2048, wgf);
    k_meanpool<<<256, 256, 0, stream>>>(imgb, avg);
    k_init<<<128, 256, 0, stream>>>(avg, Winh, binh, Winc, binc, c, hb, xhb);
    k_attimg_mfma<<<784, 256, 0, stream>>>(imgb, waf, bai, att_img);
    k_hmats_mfma<<<40, 256, 0, stream>>>(hb, whf, bah, bfb, hWatt, gate);

    // ---- timestep loop (4 kernels/step) ----
    for (int t = 0; t < TT_; t++) {
        k_energy<<<1568, 256, 0, stream>>>(att_img, hWatt, v_att, b_v, e);
        k_softmax_ctx<<<dim3(BB_, 8), 128, 0, stream>>>(e, imgb, gate, Emb, caps, t,
                                                        xhb, hb, alphas);
        k_gateslstm<<<32, 256, 0, stream>>>(xhb, wgf, bih, bhh, c, hb);
        k_out_hmats<<<509, 256, 0, stream>>>(hb, wof, bout, whf, bah, bfb,
                                             preds, hWatt, gate, t);
    }
}